// Round 7
// baseline (235.892 us; speedup 1.0000x reference)
//
#include <hip/hip_runtime.h>
#include <hip/hip_bf16.h>
#include <math.h>

#define NDIM 768
#define NHEADS 12
#define HD 64
#define SEQ 1024
#define BATCH 8
#define MROWS (BATCH * SEQ)          // 8192
#define SQRT_DIM 27.712812921102035f // 1/SCALE_PARAM_INIT
#define LOG2E 1.4426950408889634f

typedef unsigned short u16;
typedef unsigned int u32;
typedef __attribute__((ext_vector_type(8))) short short8;   // 8 bf16 = 4 VGPRs
typedef __attribute__((ext_vector_type(4))) short bf16x4;   // 4 bf16 = 2 VGPRs
typedef __attribute__((ext_vector_type(4))) float f32x4;
typedef __attribute__((ext_vector_type(16))) float f32x16;
typedef __attribute__((ext_vector_type(2))) u32 u32x2;
typedef __attribute__((ext_vector_type(4))) u32 u32x4;

#define MFMA16(a, b, c) __builtin_amdgcn_mfma_f32_16x16x32_bf16(a, b, c, 0, 0, 0)
#define MFMA32(a, b, c) __builtin_amdgcn_mfma_f32_32x32x16_bf16(a, b, c, 0, 0, 0)

#if __has_builtin(__builtin_amdgcn_exp2f)
#define EXP2(x) __builtin_amdgcn_exp2f(x)
#else
#define EXP2(x) exp2f(x)
#endif

__device__ inline u16 f2bf(float f) {
    __hip_bfloat16 h = __float2bfloat16(f);
    return *reinterpret_cast<u16*>(&h);
}

// RNE round a,b to bf16 and pack into one u32 (a = low half). No NaN check —
// callers guarantee finite inputs.
__device__ inline u32 rne_pack(float a, float b) {
    u32 ua = __builtin_bit_cast(u32, a), ub = __builtin_bit_cast(u32, b);
    ua = (ua + 0x7fffu + ((ua >> 16) & 1u)) >> 16;
    ub = (ub + 0x7fffu + ((ub >> 16) & 1u)) >> 16;
    return (ub << 16) | ua;
}

// single-instruction packed f32->bf16 RNE convert (no builtin on gfx950; T12)
__device__ inline u32 cvtpk(float a, float b) {
    u32 r;
    asm("v_cvt_pk_bf16_f32 %0, %1, %2" : "=v"(r) : "v"(a), "v"(b));
    return r;
}

// async 16B global->LDS. LDS dest is wave-uniform base; HW adds lane*16.
__device__ inline void gl2lds16(const void* g, void* l) {
    __builtin_amdgcn_global_load_lds((const __attribute__((address_space(1))) void*)g,
                                     (__attribute__((address_space(3))) void*)l, 16, 0, 0);
}

// compiler-fenced raw barrier (NO vmcnt drain — that is the whole point)
__device__ inline void bar() {
    asm volatile("" ::: "memory");
    __builtin_amdgcn_s_barrier();
    asm volatile("" ::: "memory");
}
#define LGKM0 asm volatile("s_waitcnt lgkmcnt(0)" ::: "memory")
#define VM0   asm volatile("s_waitcnt vmcnt(0)" ::: "memory")

// half-swap: x[i] = i<32 ? a[i] : b[i-32]; y[i] = i<32 ? a[i+32] : b[i].
// One v_permlane32_swap_b32 yields both outputs (T12); shfl fallback.
__device__ inline void plswap(u32 a, u32 b, int half, u32& x, u32& y) {
#if __has_builtin(__builtin_amdgcn_permlane32_swap)
    u32x2 r = __builtin_amdgcn_permlane32_swap(a, b, false, false);
    x = r[0]; y = r[1];
#else
    u32 oa = __shfl_xor(a, 32, 64), ob = __shfl_xor(b, 32, 64);
    x = half ? ob : a;
    y = half ? b : oa;
#endif
}

// ---------------------------------------------------------------------------
// One fused cast kernel: x (6144 blocks) + Wq/Wk/Wv -> Wqkv, Wo -> Wob.
// ---------------------------------------------------------------------------
__global__ __launch_bounds__(256) void castall(const float* __restrict__ x,
                                               const float* __restrict__ Wq,
                                               const float* __restrict__ Wk,
                                               const float* __restrict__ Wv,
                                               const float* __restrict__ Wo,
                                               u16* __restrict__ xb,
                                               u16* __restrict__ Wqkv,
                                               u16* __restrict__ Wob) {
    const int WB = (NDIM * NDIM) / 1024; // 576 blocks per weight
    int blk = blockIdx.x;
    const float* s;
    u16* d;
    int base;
    if (blk < 6144) {
        s = x; d = xb; base = blk * 1024;
    } else {
        int wsel = (blk - 6144) / WB, r = (blk - 6144) % WB;
        base = r * 1024;
        if (wsel == 0)      { s = Wq; d = Wqkv; }
        else if (wsel == 1) { s = Wk; d = Wqkv + NDIM * NDIM; }
        else if (wsel == 2) { s = Wv; d = Wqkv + 2 * NDIM * NDIM; }
        else                { s = Wo; d = Wob; }
    }
    int i = base + threadIdx.x * 4;
    float4 v = *(const float4*)(s + i);
    uint2 o = make_uint2(rne_pack(v.x, v.y), rne_pack(v.z, v.w));
    *(uint2*)(d + i) = o;
}

// ---------------------------------------------------------------------------
// 256x256(+sliver) / BK=64 / 8-wave 8-phase GEMM (T3+T4+T5) for the fused QKV
// projection: C = A[8192,768] @ B[2304,768]^T with fused cosine-norm (Q/K)
// and transposed-V epilogue.
//
// r7: NO tail round. 288 tiles don't fit 256 CUs, so the 9th N-strip (cols
// 2048..2303, pure V heads 8..11) is folded into the 256 full blocks: block
// (bm, nt=local&7) additionally computes the 32x256 sliver {A rows
// bm+nt*32..+32} x {B rows 2048..2303}. Sliver A comes from the block's own
// LDS A-tile (same rows, same swizzle); sliver B is read straight from L2
// (0.4 MB strip, hot on every XCD) into registers at P0 (T14 reg-staging,
// 16 rows x 64 B per instr = fully coalesced) and consumed by 8 extra MFMA
// in P1. vmcnt discipline unchanged: reg-loads are older than the in-flight
// staging loads, so P3's counted vmcnt(4) still leaves exactly B(T+2) flying.
// Prior tail attempts: r4 drain-per-iter ~19us, r5 ring ~15us, r6 64x128
// ~12us — the second round itself was the cost; this removes it.
// ---------------------------------------------------------------------------
__global__ __launch_bounds__(512, 2) void gemm256_qkv(const u16* __restrict__ A,
                                                      const u16* __restrict__ B,
                                                      u16* __restrict__ Vt,
                                                      const float* __restrict__ s_qk,
                                                      u16* __restrict__ Qdst,
                                                      u16* __restrict__ Kdst) {
    constexpr int K = NDIM;     // 768
    constexpr int NT = K / 64;  // 12 K-tiles
    __shared__ __align__(16) u16 As[2][2][128 * 64]; // [dbuf][half][r*8+slot]
    __shared__ __align__(16) u16 Bs[2][2][128 * 64];

    const int t = threadIdx.x;
    const int wave = t >> 6, lane = t & 63;
    const int quad = lane >> 4, l16 = lane & 15;
    const int fx = l16 & 7;                  // fragment-read XOR key
    const int blk = blockIdx.x;

    // half-tile stage: 128 rows x 64 k = 16 KB = 512 thr x 2 x 16B.
    const int srow = lane >> 3;
    const int schk = (lane & 7) ^ srow;
    auto stg = [&](const u16* src, u16* dst) {
#pragma unroll
        for (int it = 0; it < 2; ++it) {
            const int cb = it * 512 + wave * 64; // slot base, wave-uniform
            const int r = (cb >> 3) + srow;      // row 0..127
            gl2lds16(src + (size_t)r * K + schk * 8, (char*)dst + cb * 16);
        }
    };

    const int wm = wave >> 2, wn = wave & 3; // 2 x 4 wave grid, 128x64 each
    const int xcd = blk & 7, local = blk >> 3;            // 0..31
    const int bm = xcd * 1024 + (local >> 3) * 256;       // 4 M-tiles/XCD
    const int bn = (local & 7) * 256;                     // N-tiles 0..7
    const int nt = local & 7;                             // sliver row-slot

    f32x4 acc[8][4];
#pragma unroll
    for (int i = 0; i < 8; ++i)
#pragma unroll
        for (int j = 0; j < 4; ++j) acc[i][j] = (f32x4){0.f, 0.f, 0.f, 0.f};
    f32x4 accs[4]; // sliver acc: wave covers 16 rows x 64 cols of 32x256
#pragma unroll
    for (int j = 0; j < 4; ++j) accs[j] = (f32x4){0.f, 0.f, 0.f, 0.f};

    const u16* Ag = A + (size_t)bm * K;
    const u16* Bg = B + (size_t)bn * K;
    // sliver coords
    const int srow_s = nt * 32 + wm * 16;      // block-local A row base
    const int svhalf = srow_s >> 7;            // As half holding sliver rows
    const int slr = (srow_s & 127) + l16;      // row within half (<128)
    const u16* Bsv = B + (size_t)(2048 + wn * 64 + l16) * K; // per-lane B row

    // prologue: tile0 {A,B} + tile1 {B}; wait tile0 (12 issued, 4 may fly)
    stg(Ag,                        As[0][0]);
    stg(Ag + (size_t)128 * K,      As[0][1]);
    stg(Bg,                        Bs[0][0]);
    stg(Bg + (size_t)128 * K,      Bs[0][1]);
    stg(Bg + 64,                   Bs[1][0]);
    stg(Bg + (size_t)128 * K + 64, Bs[1][1]);
    asm volatile("s_waitcnt vmcnt(4)" ::: "memory");
    bar();

    short8 a[4][2], b0[2][2], b1[2][2];
    short8 sa_[2], sb_[4][2];
    const int rb0 = (wn & 1) * 64; // this wave's B-row base within its half

#pragma unroll 2
    for (int T = 0; T < NT; ++T) {
        const int db = T & 1;
        u16* Asl = As[db][wm];
        u16* Bsl = Bs[db][wn >> 1];
        const u16* An = Ag + (size_t)(T + 1) * 64;
        const u16* Bn = Bg + (size_t)(T + 2) * 64;

        // ---- P0: sliver-B reg loads (L2); read A[mi0-3]+B[ni0-1]+sliverA;
        //          stage A(T+1)h0; MFMA Q(0,0) ----
#pragma unroll
        for (int ni = 0; ni < 4; ++ni)
#pragma unroll
            for (int kk = 0; kk < 2; ++kk)
                sb_[ni][kk] = *(const short8*)(Bsv + (size_t)ni * 16 * K +
                                               T * 64 + (kk * 4 + quad) * 8);
#pragma unroll
        for (int mi = 0; mi < 4; ++mi) {
            const int r = mi * 16 + l16;
#pragma unroll
            for (int kk = 0; kk < 2; ++kk)
                a[mi][kk] = *(const short8*)&Asl[(r * 8 + ((kk * 4 + quad) ^ fx)) * 8];
        }
#pragma unroll
        for (int ni = 0; ni < 2; ++ni) {
            const int r = rb0 + ni * 16 + l16;
#pragma unroll
            for (int kk = 0; kk < 2; ++kk)
                b0[ni][kk] = *(const short8*)&Bsl[(r * 8 + ((kk * 4 + quad) ^ fx)) * 8];
        }
#pragma unroll
        for (int kk = 0; kk < 2; ++kk)
            sa_[kk] = *(const short8*)&As[db][svhalf][
                (slr * 8 + ((kk * 4 + quad) ^ fx)) * 8];
        if (T + 1 < NT) stg(An, As[db ^ 1][0]);
        bar();
        LGKM0;
        __builtin_amdgcn_s_setprio(1);
#pragma unroll
        for (int kk = 0; kk < 2; ++kk)
#pragma unroll
            for (int mi = 0; mi < 4; ++mi)
#pragma unroll
                for (int ni = 0; ni < 2; ++ni)
                    acc[mi][ni] = MFMA16(a[mi][kk], b0[ni][kk], acc[mi][ni]);
        __builtin_amdgcn_s_setprio(0);
        bar();

        // ---- P1: read B[ni2-3]; stage A(T+1)h1; MFMA Q(0,1) + sliver ----
#pragma unroll
        for (int ni = 0; ni < 2; ++ni) {
            const int r = rb0 + (ni + 2) * 16 + l16;
#pragma unroll
            for (int kk = 0; kk < 2; ++kk)
                b1[ni][kk] = *(const short8*)&Bsl[(r * 8 + ((kk * 4 + quad) ^ fx)) * 8];
        }
        if (T + 1 < NT) stg(An + (size_t)128 * K, As[db ^ 1][1]);
        bar();
        LGKM0;
        __builtin_amdgcn_s_setprio(1);
#pragma unroll
        for (int kk = 0; kk < 2; ++kk)
#pragma unroll
            for (int mi = 0; mi < 4; ++mi)
#pragma unroll
                for (int ni = 0; ni < 2; ++ni)
                    acc[mi][ni + 2] = MFMA16(a[mi][kk], b1[ni][kk], acc[mi][ni + 2]);
        // sliver MFMA (compiler inserts the vmcnt wait for sb_ here; the 4
        // staging loads issued after the reg-loads stay in flight)
#pragma unroll
        for (int kk = 0; kk < 2; ++kk)
#pragma unroll
            for (int ni = 0; ni < 4; ++ni)
                accs[ni] = MFMA16(sa_[kk], sb_[ni][kk], accs[ni]);
        __builtin_amdgcn_s_setprio(0);
        bar();

        // ---- P2: read A[mi4-7]; stage B(T+2)h0; MFMA Q(1,1) ----
#pragma unroll
        for (int mi = 0; mi < 4; ++mi) {
            const int r = (mi + 4) * 16 + l16;
#pragma unroll
            for (int kk = 0; kk < 2; ++kk)
                a[mi][kk] = *(const short8*)&Asl[(r * 8 + ((kk * 4 + quad) ^ fx)) * 8];
        }
        if (T + 2 < NT) stg(Bn, Bs[db][0]);
        bar();
        LGKM0;
        __builtin_amdgcn_s_setprio(1);
#pragma unroll
        for (int kk = 0; kk < 2; ++kk)
#pragma unroll
            for (int mi = 0; mi < 4; ++mi)
#pragma unroll
                for (int ni = 0; ni < 2; ++ni)
                    acc[mi + 4][ni + 2] = MFMA16(a[mi][kk], b1[ni][kk], acc[mi + 4][ni + 2]);
        __builtin_amdgcn_s_setprio(0);
        bar();

        // ---- P3: stage B(T+2)h1; MFMA Q(1,0); counted vmcnt; bar ----
        if (T + 2 < NT) stg(Bn + (size_t)128 * K, Bs[db][1]);
        bar();
        __builtin_amdgcn_s_setprio(1);
#pragma unroll
        for (int kk = 0; kk < 2; ++kk)
#pragma unroll
            for (int mi = 0; mi < 4; ++mi)
#pragma unroll
                for (int ni = 0; ni < 2; ++ni)
                    acc[mi + 4][ni] = MFMA16(a[mi][kk], b0[ni][kk], acc[mi + 4][ni]);
        __builtin_amdgcn_s_setprio(0);
        if (T + 2 < NT) {
            asm volatile("s_waitcnt vmcnt(4)" ::: "memory"); // tile T+1 resident
        } else {
            VM0; // drains A(NT-1) too (last two iters)
        }
        bar();
    }

    // ---- fused QKV epilogue (wave's 64 cols = exactly one head-group) ----
    const int cg = (bn + wn * 64) >> 6; // 0..31 here
    if (cg >= 2 * NHEADS) {
        // V path: transposed bf16 write, 4 consecutive tokens packed -> 8B
        const int h = cg - 2 * NHEADS;
#pragma unroll
        for (int mi = 0; mi < 8; ++mi) {
            const int row = bm + wm * 128 + mi * 16 + quad * 4; // token base
            const int bb = row >> 10, n0 = row & 1023;
#pragma unroll
            for (int ni = 0; ni < 4; ++ni) {
                const int dd = ni * 16 + l16;
                uint2 pk = make_uint2(rne_pack(acc[mi][ni][0], acc[mi][ni][1]),
                                      rne_pack(acc[mi][ni][2], acc[mi][ni][3]));
                *(uint2*)(Vt + (((size_t)(bb * NHEADS + h) * HD + dd) << 10) + n0) = pk;
            }
        }
    } else {
        const bool isq = cg < NHEADS;
        const int h = isq ? cg : cg - NHEADS;
        u16* dst = isq ? Qdst : Kdst;
        const float ex = isq ? 8.f * LOG2E : 1.f;
        float sq[4];
#pragma unroll
        for (int ni = 0; ni < 4; ++ni)
            sq[ni] = s_qk[h * HD + ni * 16 + l16] * SQRT_DIM * ex;
#pragma unroll
        for (int mi = 0; mi < 8; ++mi)
#pragma unroll
            for (int r = 0; r < 4; ++r) {
                float ss = 0.f;
#pragma unroll
                for (int ni = 0; ni < 4; ++ni) ss += acc[mi][ni][r] * acc[mi][ni][r];
                ss += __shfl_xor(ss, 1, 64);
                ss += __shfl_xor(ss, 2, 64);
                ss += __shfl_xor(ss, 4, 64);
                ss += __shfl_xor(ss, 8, 64);
                float inv = 1.f / fmaxf(sqrtf(ss), 1e-6f);
                const int row = bm + wm * 128 + mi * 16 + quad * 4 + r;
                const int bb = row >> 10, tok = row & 1023;
                u16* o = dst + ((size_t)(bb * NHEADS + h) * SEQ + tok) * HD;
#pragma unroll
                for (int ni = 0; ni < 4; ++ni)
                    o[ni * 16 + l16] = f2bf(acc[mi][ni][r] * sq[ni] * inv);
            }
    }
    // ---- sliver epilogue (all waves): V heads 8..11, transposed write ----
    {
        const int row0 = bm + nt * 32 + wm * 16 + quad * 4;
        const int bb = row0 >> 10, n0 = row0 & 1023;
#pragma unroll
        for (int ni = 0; ni < 4; ++ni) {
            const int cv = wn * 64 + ni * 16 + l16; // 0..255 within the strip
            const int h = 8 + (cv >> 6), dd = cv & 63;
            uint2 pk = make_uint2(rne_pack(accs[ni][0], accs[ni][1]),
                                  rne_pack(accs[ni][2], accs[ni][3]));
            *(uint2*)(Vt + (((size_t)(bb * NHEADS + h) * HD + dd) << 10) + n0) = pk;
        }
    }
}

// ---------------------------------------------------------------------------
// bf16 MFMA GEMM: C = A[M,768] @ B[N,768]^T, fp32 accum. 128x128 tile,
// double-buffered BK=32 (one barrier/iter). Kept for the output projection.
// ---------------------------------------------------------------------------
template <int EPI>
__global__ __launch_bounds__(256) void gemm_bf16(const u16* __restrict__ A,
                                                 const u16* __restrict__ B,
                                                 void* __restrict__ C, int N,
                                                 const float* __restrict__ s_qk,
                                                 u16* __restrict__ Qdst,
                                                 u16* __restrict__ Kdst,
                                                 int NX) {
    constexpr int K = NDIM;
    constexpr int NKT = K / 32; // 24 K-tiles
    __shared__ __align__(16) u16 As[2][4096]; // 8 KB per buffer
    __shared__ __align__(16) u16 Bs[2][4096];
    const int t = threadIdx.x;
    const int wave = t >> 6, lane = t & 63;
    const int quad = lane >> 4, l16 = lane & 15;
    const int wx = (wave & 1) * 64, wy = (wave >> 1) * 64;
    const int blk = blockIdx.x;
    const int xcd = blk & 7, local = blk >> 3;
    const int bm = (xcd * 8 + local / NX) * 128;
    const int bn = (local % NX) * 128;

    f32x4 acc[4][4];
#pragma unroll
    for (int i = 0; i < 4; ++i)
#pragma unroll
        for (int j = 0; j < 4; ++j) acc[i][j] = (f32x4){0.f, 0.f, 0.f, 0.f};

    const int srl = lane >> 2;
    const int skc = (lane & 3) ^ ((lane >> 3) & 3);
    auto stage = [&](int k0, int bsel) {
#pragma unroll
        for (int it = 0; it < 2; ++it) {
            const int cb = it * 256 + wave * 64;
            const int row = (cb >> 6) * 16 + srl;
            gl2lds16(A + (size_t)(bm + row) * K + k0 + skc * 8,
                     (char*)As[bsel] + cb * 16);
            gl2lds16(B + (size_t)(bn + row) * K + k0 + skc * 8,
                     (char*)Bs[bsel] + cb * 16);
        }
    };
    const int fxor = (l16 >> 1) & 3;

    stage(0, 0);
#pragma unroll
    for (int kt = 0; kt < NKT; ++kt) {
        __syncthreads();
        if (kt + 1 < NKT) stage((kt + 1) * 32, (kt + 1) & 1);
        const int b = kt & 1;
        short8 af[4], bfr[4];
#pragma unroll
        for (int i = 0; i < 4; ++i)
            af[i] = *(const short8*)&As[b][
                ((((wy >> 4) + i) * 64 + l16 * 4 + (quad ^ fxor)) * 8)];
#pragma unroll
        for (int j = 0; j < 4; ++j)
            bfr[j] = *(const short8*)&Bs[b][
                ((((wx >> 4) + j) * 64 + l16 * 4 + (quad ^ fxor)) * 8)];
#pragma unroll
        for (int i = 0; i < 4; ++i)
#pragma unroll
            for (int j = 0; j < 4; ++j) acc[i][j] = MFMA16(af[i], bfr[j], acc[i][j]);
    }

    if constexpr (EPI == 0) {
#pragma unroll
        for (int i = 0; i < 4; ++i)
#pragma unroll
            for (int j = 0; j < 4; ++j)
#pragma unroll
                for (int r = 0; r < 4; ++r) {
                    const int row = bm + wy + i * 16 + quad * 4 + r;
                    const int col = bn + wx + j * 16 + l16;
                    ((float*)C)[(size_t)row * N + col] = acc[i][j][r];
                }
    }
}

// ---------------------------------------------------------------------------
// MFMA flash attention, 32x32x16, no-max softmax. 256 threads = 4 waves;
// each wave owns 32 queries -> block = 128 queries; streams 64-key tiles.
// __launch_bounds__(256,3): 3 waves/EU = grid's 3 blocks/CU while allowing
// ~168 VGPR (r3 shipped at 64 VGPR -> remat VALU storm).
// ---------------------------------------------------------------------------
__global__ __launch_bounds__(256, 3) void attn_mfma(const u16* __restrict__ Qh,
                                                    const u16* __restrict__ Kh,
                                                    const u16* __restrict__ Vt,
                                                    u16* __restrict__ AO) {
    __shared__ __align__(16) u16 Ks[2][512 * 8];
    __shared__ __align__(16) u16 Vs[2][512 * 8];

    const int t = threadIdx.x;
    const int wave = t >> 6, lane = t & 63;
    const int l31 = lane & 31, half = lane >> 5;

    // XCD-grouped decode: bid&7 -> XCD slot; 12 (b,h) per XCD; 8 q-blocks each
    const int bid = blockIdx.x;
    const int xcd = bid & 7, idx = bid >> 3;      // idx 0..95
    const int bh = xcd * 12 + (idx % 12);
    const int q0 = (idx / 12) * 128;
    const int b = bh / NHEADS, h = bh - b * NHEADS;

    const u16* Kb = Kh + (size_t)bh * SEQ * HD;
    const u16* Vb = Vt + (size_t)bh * HD * SEQ;
    const int qb = q0 + wave * 32;

    // Q fragments (B-operand: n = query = l31, k = tt*16 + half*8 + j)
    short8 qf[4];
#pragma unroll
    for (int tt = 0; tt < 4; ++tt)
        qf[tt] = *(const short8*)(Qh + ((size_t)bh * SEQ + qb + l31) * HD +
                                  tt * 16 + half * 8);

    f32x16 o[2]; // [d-tile]
#pragma unroll
    for (int dt = 0; dt < 2; ++dt)
#pragma unroll
        for (int r = 0; r < 16; ++r) o[dt][r] = 0.f;
    float lp = 0.f;

    // staging lane->global mapping (inverse of slot swizzle)
    const int arl = lane >> 3;            // row within 8-row span
    const int acc8 = (lane & 7) ^ arl;    // chunk 0..7
    // fragment-read bank spread piece
    const int fx8 = l31 & 7;

    auto stage = [&](int j0, int db) {
#pragma unroll
        for (int it = 0; it < 2; ++it) {
            const int cb = it * 256 + wave * 64; // span base, wave-uniform
            const int r0 = (cb >> 6) * 8 + arl;  // row 0..63
            gl2lds16(Kb + (size_t)(j0 + r0) * HD + acc8 * 8,
                     (char*)Ks[db] + cb * 16);
            gl2lds16(Vb + (size_t)r0 * SEQ + j0 + acc8 * 8,
                     (char*)Vs[db] + cb * 16);
        }
    };

    stage(0, 0);
#pragma unroll 2
    for (int jt = 0; jt < SEQ / 64; ++jt) {
        const int db = jt & 1;
        VM0;   // own tile-jt loads done (issued one full compute phase ago)
        bar(); // all waves' loads landed; all waves done reading buf db^1
        if (jt + 1 < SEQ / 64) stage((jt + 1) * 64, db ^ 1);
        const u16* Ksl = Ks[db];
        const u16* Vsl = Vs[db];

        // ---- S^T: both 32-key tiles, independent MFMA chains first ----
        f32x16 sa0, sa1;
#pragma unroll
        for (int r = 0; r < 16; ++r) { sa0[r] = 0.f; sa1[r] = 0.f; }
#pragma unroll
        for (int tt = 0; tt < 4; ++tt) {
            short8 kf0 = *(const short8*)&Ksl[
                ((((l31 >> 3)) * 64) + fx8 * 8 + ((2 * tt + half) ^ fx8)) * 8];
            short8 kf1 = *(const short8*)&Ksl[
                (((4 + (l31 >> 3)) * 64) + fx8 * 8 + ((2 * tt + half) ^ fx8)) * 8];
            sa0 = MFMA32(kf0, qf[tt], sa0);
            sa1 = MFMA32(kf1, qf[tt], sa1);
        }

        // ---- softmax numerators in-register (exp2 -> cvt_pk -> permlane) ----
        short8 pf0a, pf0b, pf1a, pf1b;
        {
            float p[16];
#pragma unroll
            for (int r = 0; r < 16; ++r) p[r] = EXP2(sa0[r]);
#pragma unroll
            for (int rg = 0; rg < 4; ++rg)
                lp += (p[rg * 4] + p[rg * 4 + 1]) + (p[rg * 4 + 2] + p[rg * 4 + 3]);
            u32 q[8];
#pragma unroll
            for (int i = 0; i < 8; ++i) q[i] = cvtpk(p[2 * i], p[2 * i + 1]);
            u32 d0, d1, d2, d3, e0, e1, e2, e3;
            plswap(q[0], q[2], half, d0, d2);
            plswap(q[1], q[3], half, d1, d3);
            plswap(q[4], q[6], half, e0, e2);
            plswap(q[5], q[7], half, e1, e3);
            u32x4 f0v = {d0, d1, d2, d3};
            u32x4 f1v = {e0, e1, e2, e3};
            pf0a = __builtin_bit_cast(short8, f0v);
            pf0b = __builtin_bit_cast(short8, f1v);
        }
        {
            float p[16];
#pragma unroll
            for (int r = 0; r < 16; ++r) p[r] = EXP2(sa1[r]);
#pragma unroll
            for (int rg = 0; rg < 4; ++rg)
                lp += (p[rg * 4] + p[rg * 4 + 1]) + (p[rg * 4 + 2] + p[rg * 4 + 3]);
            u32 q[8];
#pragma unroll
            for (int i = 0; i < 8; ++i) q[i] = cvtpk(p[2 * i], p[2 * i + 1]);
            u32 d0, d1, d2, d3, e0, e1, e2, e3;
            plswap(q[0], q[2], half, d0, d2);
            plswap(q[1], q[3], half, d1, d3);
            plswap(q[4], q[6], half, e0, e2);
            plswap(q[5], q[7], half, e1, e3);
            u32x4 f0v = {d0, d1, d2, d3};
            u32x4 f1v = {e0, e1, e2, e3};
            pf1a = __builtin_bit_cast(short8, f0v);
            pf1b = __builtin_bit_cast(short8, f1v);
        }

        // ---- PV: O^T += V^T @ P (4 slices of 16 keys) ----
#pragma unroll
        for (int kt = 0; kt < 2; ++kt)
#pragma unroll
            for (int s = 0; s < 2; ++s) {
                short8 pf = kt ? (s ? pf1b : pf1a) : (s ? pf0b : pf0a);
                const int c = kt * 4 + s * 2 + half; // key-slice column
#pragma unroll
                for (int dt = 0; dt < 2; ++dt) {
                    short8 vf = *(const short8*)&Vsl[
                        (((dt * 4 + (l31 >> 3)) * 64) + fx8 * 8 + (c ^ fx8)) * 8];
                    o[dt] = MFMA32(vf, pf, o[dt]);
                }
            }
    }

    // final l reduction (halves hold disjoint key subsets) and output
    const float invl = 1.f / (lp + __shfl_xor(lp, 32, 64));
    u16* ob = AO + (size_t)(b * SEQ + qb + l31) * NDIM + h * HD;
#pragma unroll
    for (int dt = 0; dt < 2; ++dt)
#pragma unroll
        for (int rg = 0; rg < 4; ++rg) {
            bf16x4 ok = {(short)f2bf(o[dt][rg * 4 + 0] * invl),
                         (short)f2bf(o[dt][rg * 4 + 1] * invl),
                         (short)f2bf(o[dt][rg * 4 + 2] * invl),
                         (short)f2bf(o[dt][rg * 4 + 3] * invl)};
            *(bf16x4*)(ob + dt * 32 + rg * 8 + half * 4) = ok;
        }
}

// ---------------------------------------------------------------------------
extern "C" void kernel_launch(void* const* d_in, const int* in_sizes, int n_in,
                              void* d_out, int out_size, void* d_ws, size_t ws_size,
                              hipStream_t stream) {
    const float* x    = (const float*)d_in[0];
    const float* Wq   = (const float*)d_in[1];
    const float* Wk   = (const float*)d_in[2];
    const float* Wv   = (const float*)d_in[3];
    const float* Wo   = (const float*)d_in[4];
    const float* s_qk = (const float*)d_in[5];
    float* out = (float*)d_out;

    char* w = (char*)d_ws;
    const size_t TE = (size_t)MROWS * NDIM;
    u16* xb   = (u16*)w;                    w += TE * 2;
    u16* Wqkv = (u16*)w;                    w += (size_t)3 * NDIM * NDIM * 2;
    u16* Wob  = (u16*)w;                    w += (size_t)NDIM * NDIM * 2;
    u16* Qh   = (u16*)w;                    w += TE * 2;
    u16* Kh   = (u16*)w;                    w += TE * 2;
    u16* Vt   = (u16*)w;                    w += TE * 2;
    u16* ao   = (u16*)w;

    castall<<<6144 + 4 * 576, 256, 0, stream>>>(x, Wq, Wk, Wv, Wo, xb, Wqkv, Wob);

    // Fused QKV projection: 256 uniform blocks (256^2 tile + 32x256 sliver
    // of the 9th N-strip each) — exactly one scheduling round, no tail.
    gemm256_qkv<<<256, 512, 0, stream>>>(xb, Wqkv, Vt, s_qk, Qh, Kh);

    // Flash attention, XCD-grouped 1D grid (768 = 8 xcd x 12 bh x 8 qblk)
    attn_mfma<<<768, 256, 0, stream>>>(Qh, Kh, Vt, ao);

    // Output projection: NX = 768/128 = 6
    gemm_bf16<0><<<6 * 64, 256, 0, stream>>>(
        ao, Wob, out, NDIM, nullptr, nullptr, nullptr, 6);
}

// Round 8
// 191.232 us; speedup vs baseline: 1.2335x; 1.2335x over previous
//
#include <hip/hip_runtime.h>
#include <hip/hip_bf16.h>
#include <math.h>

#define NDIM 768
#define NHEADS 12
#define HD 64
#define SEQ 1024
#define BATCH 8
#define MROWS (BATCH * SEQ)          // 8192
#define SQRT_DIM 27.712812921102035f // 1/SCALE_PARAM_INIT
#define LOG2E 1.4426950408889634f

typedef unsigned short u16;
typedef unsigned int u32;
typedef __attribute__((ext_vector_type(8))) short short8;   // 8 bf16 = 4 VGPRs
typedef __attribute__((ext_vector_type(4))) short bf16x4;   // 4 bf16 = 2 VGPRs
typedef __attribute__((ext_vector_type(4))) float f32x4;
typedef __attribute__((ext_vector_type(16))) float f32x16;
typedef __attribute__((ext_vector_type(2))) u32 u32x2;
typedef __attribute__((ext_vector_type(4))) u32 u32x4;

#define MFMA16(a, b, c) __builtin_amdgcn_mfma_f32_16x16x32_bf16(a, b, c, 0, 0, 0)
#define MFMA32(a, b, c) __builtin_amdgcn_mfma_f32_32x32x16_bf16(a, b, c, 0, 0, 0)

#if __has_builtin(__builtin_amdgcn_exp2f)
#define EXP2(x) __builtin_amdgcn_exp2f(x)
#else
#define EXP2(x) exp2f(x)
#endif

__device__ inline u16 f2bf(float f) {
    __hip_bfloat16 h = __float2bfloat16(f);
    return *reinterpret_cast<u16*>(&h);
}

// RNE round a,b to bf16 and pack into one u32 (a = low half). No NaN check —
// callers guarantee finite inputs.
__device__ inline u32 rne_pack(float a, float b) {
    u32 ua = __builtin_bit_cast(u32, a), ub = __builtin_bit_cast(u32, b);
    ua = (ua + 0x7fffu + ((ua >> 16) & 1u)) >> 16;
    ub = (ub + 0x7fffu + ((ub >> 16) & 1u)) >> 16;
    return (ub << 16) | ua;
}

// single-instruction packed f32->bf16 RNE convert (no builtin on gfx950; T12)
__device__ inline u32 cvtpk(float a, float b) {
    u32 r;
    asm("v_cvt_pk_bf16_f32 %0, %1, %2" : "=v"(r) : "v"(a), "v"(b));
    return r;
}

// async 16B global->LDS. LDS dest is wave-uniform base; HW adds lane*16.
__device__ inline void gl2lds16(const void* g, void* l) {
    __builtin_amdgcn_global_load_lds((const __attribute__((address_space(1))) void*)g,
                                     (__attribute__((address_space(3))) void*)l, 16, 0, 0);
}

// compiler-fenced raw barrier (NO vmcnt drain — that is the whole point)
__device__ inline void bar() {
    asm volatile("" ::: "memory");
    __builtin_amdgcn_s_barrier();
    asm volatile("" ::: "memory");
}
#define LGKM0 asm volatile("s_waitcnt lgkmcnt(0)" ::: "memory")
#define VM0   asm volatile("s_waitcnt vmcnt(0)" ::: "memory")

// half-swap: x[i] = i<32 ? a[i] : b[i-32]; y[i] = i<32 ? a[i+32] : b[i].
// One v_permlane32_swap_b32 yields both outputs (T12); shfl fallback.
__device__ inline void plswap(u32 a, u32 b, int half, u32& x, u32& y) {
#if __has_builtin(__builtin_amdgcn_permlane32_swap)
    u32x2 r = __builtin_amdgcn_permlane32_swap(a, b, false, false);
    x = r[0]; y = r[1];
#else
    u32 oa = __shfl_xor(a, 32, 64), ob = __shfl_xor(b, 32, 64);
    x = half ? ob : a;
    y = half ? b : oa;
#endif
}

// ---------------------------------------------------------------------------
// One fused cast kernel: x (6144 blocks) + Wq/Wk/Wv -> Wqkv, Wo -> Wob.
// ---------------------------------------------------------------------------
__global__ __launch_bounds__(256) void castall(const float* __restrict__ x,
                                               const float* __restrict__ Wq,
                                               const float* __restrict__ Wk,
                                               const float* __restrict__ Wv,
                                               const float* __restrict__ Wo,
                                               u16* __restrict__ xb,
                                               u16* __restrict__ Wqkv,
                                               u16* __restrict__ Wob) {
    const int WB = (NDIM * NDIM) / 1024; // 576 blocks per weight
    int blk = blockIdx.x;
    const float* s;
    u16* d;
    int base;
    if (blk < 6144) {
        s = x; d = xb; base = blk * 1024;
    } else {
        int wsel = (blk - 6144) / WB, r = (blk - 6144) % WB;
        base = r * 1024;
        if (wsel == 0)      { s = Wq; d = Wqkv; }
        else if (wsel == 1) { s = Wk; d = Wqkv + NDIM * NDIM; }
        else if (wsel == 2) { s = Wv; d = Wqkv + 2 * NDIM * NDIM; }
        else                { s = Wo; d = Wob; }
    }
    int i = base + threadIdx.x * 4;
    float4 v = *(const float4*)(s + i);
    uint2 o = make_uint2(rne_pack(v.x, v.y), rne_pack(v.z, v.w));
    *(uint2*)(d + i) = o;
}

// ---------------------------------------------------------------------------
// 256x256(+sliver) / BK=64 / 8-wave 8-phase GEMM (T3+T4+T5) for the fused QKV
// projection: C = A[8192,768] @ B[2304,768]^T with fused cosine-norm (Q/K)
// and transposed-V epilogue. Grid = 256 blocks, exactly one round, no tail.
//
// The 9th N-strip (cols 2048..2303, pure V heads 8..11) is folded in: block
// (bm, nt=local&7) computes the 32x256 sliver {A rows bm+nt*32..+32} x
// {B rows 2048..2303} in a SHORT POST-LOOP (register-only, A/B from L2).
// r7 LESSON: putting the sliver INSIDE the main loop spilled — the main loop
// is already at the 256-reg/lane cap (128 acc + 128 arch); +56 live regs ->
// scratch (WRITE_SIZE 37->83 MB, 3x slowdown). Post-loop, acc[8][4] is dead,
// so peak pressure is unchanged. #pragma unroll 2 (not full) so the
// scheduler can't hoist all 120 loads and re-create the spill.
// ---------------------------------------------------------------------------
__global__ __launch_bounds__(512, 2) void gemm256_qkv(const u16* __restrict__ A,
                                                      const u16* __restrict__ B,
                                                      u16* __restrict__ Vt,
                                                      const float* __restrict__ s_qk,
                                                      u16* __restrict__ Qdst,
                                                      u16* __restrict__ Kdst) {
    constexpr int K = NDIM;     // 768
    constexpr int NT = K / 64;  // 12 K-tiles
    __shared__ __align__(16) u16 As[2][2][128 * 64]; // [dbuf][half][r*8+slot]
    __shared__ __align__(16) u16 Bs[2][2][128 * 64];

    const int t = threadIdx.x;
    const int wave = t >> 6, lane = t & 63;
    const int quad = lane >> 4, l16 = lane & 15;
    const int fx = l16 & 7;                  // fragment-read XOR key
    const int blk = blockIdx.x;

    // half-tile stage: 128 rows x 64 k = 16 KB = 512 thr x 2 x 16B.
    const int srow = lane >> 3;
    const int schk = (lane & 7) ^ srow;
    auto stg = [&](const u16* src, u16* dst) {
#pragma unroll
        for (int it = 0; it < 2; ++it) {
            const int cb = it * 512 + wave * 64; // slot base, wave-uniform
            const int r = (cb >> 3) + srow;      // row 0..127
            gl2lds16(src + (size_t)r * K + schk * 8, (char*)dst + cb * 16);
        }
    };

    const int wm = wave >> 2, wn = wave & 3; // 2 x 4 wave grid, 128x64 each
    const int xcd = blk & 7, local = blk >> 3;            // 0..31
    const int bm = xcd * 1024 + (local >> 3) * 256;       // 4 M-tiles/XCD
    const int bn = (local & 7) * 256;                     // N-tiles 0..7
    const int nt = local & 7;                             // sliver row-slot

    f32x4 acc[8][4];
#pragma unroll
    for (int i = 0; i < 8; ++i)
#pragma unroll
        for (int j = 0; j < 4; ++j) acc[i][j] = (f32x4){0.f, 0.f, 0.f, 0.f};

    const u16* Ag = A + (size_t)bm * K;
    const u16* Bg = B + (size_t)bn * K;

    // prologue: tile0 {A,B} + tile1 {B}; wait tile0 (12 issued, 4 may fly)
    stg(Ag,                        As[0][0]);
    stg(Ag + (size_t)128 * K,      As[0][1]);
    stg(Bg,                        Bs[0][0]);
    stg(Bg + (size_t)128 * K,      Bs[0][1]);
    stg(Bg + 64,                   Bs[1][0]);
    stg(Bg + (size_t)128 * K + 64, Bs[1][1]);
    asm volatile("s_waitcnt vmcnt(4)" ::: "memory");
    bar();

    short8 a[4][2], b0[2][2], b1[2][2];
    const int rb0 = (wn & 1) * 64; // this wave's B-row base within its half

#pragma unroll 2
    for (int T = 0; T < NT; ++T) {
        const int db = T & 1;
        u16* Asl = As[db][wm];
        u16* Bsl = Bs[db][wn >> 1];
        const u16* An = Ag + (size_t)(T + 1) * 64;
        const u16* Bn = Bg + (size_t)(T + 2) * 64;

        // ---- P0: read A[mi0-3] + B[ni0-1]; stage A(T+1)h0; MFMA Q(0,0) ----
#pragma unroll
        for (int mi = 0; mi < 4; ++mi) {
            const int r = mi * 16 + l16;
#pragma unroll
            for (int kk = 0; kk < 2; ++kk)
                a[mi][kk] = *(const short8*)&Asl[(r * 8 + ((kk * 4 + quad) ^ fx)) * 8];
        }
#pragma unroll
        for (int ni = 0; ni < 2; ++ni) {
            const int r = rb0 + ni * 16 + l16;
#pragma unroll
            for (int kk = 0; kk < 2; ++kk)
                b0[ni][kk] = *(const short8*)&Bsl[(r * 8 + ((kk * 4 + quad) ^ fx)) * 8];
        }
        if (T + 1 < NT) stg(An, As[db ^ 1][0]);
        bar();
        LGKM0;
        __builtin_amdgcn_s_setprio(1);
#pragma unroll
        for (int kk = 0; kk < 2; ++kk)
#pragma unroll
            for (int mi = 0; mi < 4; ++mi)
#pragma unroll
                for (int ni = 0; ni < 2; ++ni)
                    acc[mi][ni] = MFMA16(a[mi][kk], b0[ni][kk], acc[mi][ni]);
        __builtin_amdgcn_s_setprio(0);
        bar();

        // ---- P1: read B[ni2-3]; stage A(T+1)h1; MFMA Q(0,1) ----
#pragma unroll
        for (int ni = 0; ni < 2; ++ni) {
            const int r = rb0 + (ni + 2) * 16 + l16;
#pragma unroll
            for (int kk = 0; kk < 2; ++kk)
                b1[ni][kk] = *(const short8*)&Bsl[(r * 8 + ((kk * 4 + quad) ^ fx)) * 8];
        }
        if (T + 1 < NT) stg(An + (size_t)128 * K, As[db ^ 1][1]);
        bar();
        LGKM0;
        __builtin_amdgcn_s_setprio(1);
#pragma unroll
        for (int kk = 0; kk < 2; ++kk)
#pragma unroll
            for (int mi = 0; mi < 4; ++mi)
#pragma unroll
                for (int ni = 0; ni < 2; ++ni)
                    acc[mi][ni + 2] = MFMA16(a[mi][kk], b1[ni][kk], acc[mi][ni + 2]);
        __builtin_amdgcn_s_setprio(0);
        bar();

        // ---- P2: read A[mi4-7]; stage B(T+2)h0; MFMA Q(1,1) ----
#pragma unroll
        for (int mi = 0; mi < 4; ++mi) {
            const int r = (mi + 4) * 16 + l16;
#pragma unroll
            for (int kk = 0; kk < 2; ++kk)
                a[mi][kk] = *(const short8*)&Asl[(r * 8 + ((kk * 4 + quad) ^ fx)) * 8];
        }
        if (T + 2 < NT) stg(Bn, Bs[db][0]);
        bar();
        LGKM0;
        __builtin_amdgcn_s_setprio(1);
#pragma unroll
        for (int kk = 0; kk < 2; ++kk)
#pragma unroll
            for (int mi = 0; mi < 4; ++mi)
#pragma unroll
                for (int ni = 0; ni < 2; ++ni)
                    acc[mi + 4][ni + 2] = MFMA16(a[mi][kk], b1[ni][kk], acc[mi + 4][ni + 2]);
        __builtin_amdgcn_s_setprio(0);
        bar();

        // ---- P3: stage B(T+2)h1; MFMA Q(1,0); counted vmcnt; bar ----
        if (T + 2 < NT) stg(Bn + (size_t)128 * K, Bs[db][1]);
        bar();
        __builtin_amdgcn_s_setprio(1);
#pragma unroll
        for (int kk = 0; kk < 2; ++kk)
#pragma unroll
            for (int mi = 0; mi < 4; ++mi)
#pragma unroll
                for (int ni = 0; ni < 2; ++ni)
                    acc[mi + 4][ni] = MFMA16(a[mi][kk], b0[ni][kk], acc[mi + 4][ni]);
        __builtin_amdgcn_s_setprio(0);
        if (T + 2 < NT) {
            asm volatile("s_waitcnt vmcnt(4)" ::: "memory"); // tile T+1 resident
        } else {
            VM0; // drains A(NT-1) too (last two iters)
        }
        bar();
    }

    // ---- fused QKV epilogue (wave's 64 cols = exactly one head-group) ----
    const int cg = (bn + wn * 64) >> 6; // 0..31 here
    if (cg >= 2 * NHEADS) {
        // V path: transposed bf16 write, 4 consecutive tokens packed -> 8B
        const int h = cg - 2 * NHEADS;
#pragma unroll
        for (int mi = 0; mi < 8; ++mi) {
            const int row = bm + wm * 128 + mi * 16 + quad * 4; // token base
            const int bb = row >> 10, n0 = row & 1023;
#pragma unroll
            for (int ni = 0; ni < 4; ++ni) {
                const int dd = ni * 16 + l16;
                uint2 pk = make_uint2(rne_pack(acc[mi][ni][0], acc[mi][ni][1]),
                                      rne_pack(acc[mi][ni][2], acc[mi][ni][3]));
                *(uint2*)(Vt + (((size_t)(bb * NHEADS + h) * HD + dd) << 10) + n0) = pk;
            }
        }
    } else {
        const bool isq = cg < NHEADS;
        const int h = isq ? cg : cg - NHEADS;
        u16* dst = isq ? Qdst : Kdst;
        const float ex = isq ? 8.f * LOG2E : 1.f;
        float sq[4];
#pragma unroll
        for (int ni = 0; ni < 4; ++ni)
            sq[ni] = s_qk[h * HD + ni * 16 + l16] * SQRT_DIM * ex;
#pragma unroll
        for (int mi = 0; mi < 8; ++mi)
#pragma unroll
            for (int r = 0; r < 4; ++r) {
                float ss = 0.f;
#pragma unroll
                for (int ni = 0; ni < 4; ++ni) ss += acc[mi][ni][r] * acc[mi][ni][r];
                ss += __shfl_xor(ss, 1, 64);
                ss += __shfl_xor(ss, 2, 64);
                ss += __shfl_xor(ss, 4, 64);
                ss += __shfl_xor(ss, 8, 64);
                float inv = 1.f / fmaxf(sqrtf(ss), 1e-6f);
                const int row = bm + wm * 128 + mi * 16 + quad * 4 + r;
                const int bb = row >> 10, tok = row & 1023;
                u16* o = dst + ((size_t)(bb * NHEADS + h) * SEQ + tok) * HD;
#pragma unroll
                for (int ni = 0; ni < 4; ++ni)
                    o[ni * 16 + l16] = f2bf(acc[mi][ni][r] * sq[ni] * inv);
            }
    }

    // ---- sliver: 32x256 of the 9th N-strip, post-loop, register-only ----
    // A rows are this block's own rows (L2-hot); B strip is 0.4 MB (L2-hot
    // on every XCD). acc[8][4] is dead here -> no extra peak reg pressure.
    {
        f32x4 accs[4];
#pragma unroll
        for (int j = 0; j < 4; ++j) accs[j] = (f32x4){0.f, 0.f, 0.f, 0.f};
        const u16* Asv = A + (size_t)(bm + nt * 32 + wm * 16 + l16) * K;
        const u16* Bsv = B + (size_t)(2048 + wn * 64 + l16) * K;
#pragma unroll 2
        for (int T = 0; T < NT; ++T) {
            short8 sa_[2], sb_[4][2];
#pragma unroll
            for (int kk = 0; kk < 2; ++kk)
                sa_[kk] = *(const short8*)(Asv + T * 64 + (kk * 4 + quad) * 8);
#pragma unroll
            for (int ni = 0; ni < 4; ++ni)
#pragma unroll
                for (int kk = 0; kk < 2; ++kk)
                    sb_[ni][kk] = *(const short8*)(Bsv + (size_t)ni * 16 * K +
                                                   T * 64 + (kk * 4 + quad) * 8);
#pragma unroll
            for (int kk = 0; kk < 2; ++kk)
#pragma unroll
                for (int ni = 0; ni < 4; ++ni)
                    accs[ni] = MFMA16(sa_[kk], sb_[ni][kk], accs[ni]);
        }
        // sliver epilogue: V heads 8..11, transposed write, 4 tokens -> 8B
        const int row0 = bm + nt * 32 + wm * 16 + quad * 4;
        const int bb = row0 >> 10, n0 = row0 & 1023;
#pragma unroll
        for (int ni = 0; ni < 4; ++ni) {
            const int cv = wn * 64 + ni * 16 + l16; // 0..255 within the strip
            const int h = 8 + (cv >> 6), dd = cv & 63;
            uint2 pk = make_uint2(rne_pack(accs[ni][0], accs[ni][1]),
                                  rne_pack(accs[ni][2], accs[ni][3]));
            *(uint2*)(Vt + (((size_t)(bb * NHEADS + h) * HD + dd) << 10) + n0) = pk;
        }
    }
}

// ---------------------------------------------------------------------------
// bf16 MFMA GEMM: C = A[M,768] @ B[N,768]^T, fp32 accum. 128x128 tile,
// double-buffered BK=32 (one barrier/iter). Kept for the output projection.
// ---------------------------------------------------------------------------
template <int EPI>
__global__ __launch_bounds__(256) void gemm_bf16(const u16* __restrict__ A,
                                                 const u16* __restrict__ B,
                                                 void* __restrict__ C, int N,
                                                 const float* __restrict__ s_qk,
                                                 u16* __restrict__ Qdst,
                                                 u16* __restrict__ Kdst,
                                                 int NX) {
    constexpr int K = NDIM;
    constexpr int NKT = K / 32; // 24 K-tiles
    __shared__ __align__(16) u16 As[2][4096]; // 8 KB per buffer
    __shared__ __align__(16) u16 Bs[2][4096];
    const int t = threadIdx.x;
    const int wave = t >> 6, lane = t & 63;
    const int quad = lane >> 4, l16 = lane & 15;
    const int wx = (wave & 1) * 64, wy = (wave >> 1) * 64;
    const int blk = blockIdx.x;
    const int xcd = blk & 7, local = blk >> 3;
    const int bm = (xcd * 8 + local / NX) * 128;
    const int bn = (local % NX) * 128;

    f32x4 acc[4][4];
#pragma unroll
    for (int i = 0; i < 4; ++i)
#pragma unroll
        for (int j = 0; j < 4; ++j) acc[i][j] = (f32x4){0.f, 0.f, 0.f, 0.f};

    const int srl = lane >> 2;
    const int skc = (lane & 3) ^ ((lane >> 3) & 3);
    auto stage = [&](int k0, int bsel) {
#pragma unroll
        for (int it = 0; it < 2; ++it) {
            const int cb = it * 256 + wave * 64;
            const int row = (cb >> 6) * 16 + srl;
            gl2lds16(A + (size_t)(bm + row) * K + k0 + skc * 8,
                     (char*)As[bsel] + cb * 16);
            gl2lds16(B + (size_t)(bn + row) * K + k0 + skc * 8,
                     (char*)Bs[bsel] + cb * 16);
        }
    };
    const int fxor = (l16 >> 1) & 3;

    stage(0, 0);
#pragma unroll
    for (int kt = 0; kt < NKT; ++kt) {
        __syncthreads();
        if (kt + 1 < NKT) stage((kt + 1) * 32, (kt + 1) & 1);
        const int b = kt & 1;
        short8 af[4], bfr[4];
#pragma unroll
        for (int i = 0; i < 4; ++i)
            af[i] = *(const short8*)&As[b][
                ((((wy >> 4) + i) * 64 + l16 * 4 + (quad ^ fxor)) * 8)];
#pragma unroll
        for (int j = 0; j < 4; ++j)
            bfr[j] = *(const short8*)&Bs[b][
                ((((wx >> 4) + j) * 64 + l16 * 4 + (quad ^ fxor)) * 8)];
#pragma unroll
        for (int i = 0; i < 4; ++i)
#pragma unroll
            for (int j = 0; j < 4; ++j) acc[i][j] = MFMA16(af[i], bfr[j], acc[i][j]);
    }

    if constexpr (EPI == 0) {
#pragma unroll
        for (int i = 0; i < 4; ++i)
#pragma unroll
            for (int j = 0; j < 4; ++j)
#pragma unroll
                for (int r = 0; r < 4; ++r) {
                    const int row = bm + wy + i * 16 + quad * 4 + r;
                    const int col = bn + wx + j * 16 + l16;
                    ((float*)C)[(size_t)row * N + col] = acc[i][j][r];
                }
    }
}

// ---------------------------------------------------------------------------
// MFMA flash attention, 32x32x16, no-max softmax. 256 threads = 4 waves;
// each wave owns 32 queries -> block = 128 queries; streams 64-key tiles.
// __launch_bounds__(256,3): 3 waves/EU = grid's 3 blocks/CU while allowing
// ~168 VGPR (r3 shipped at 64 VGPR -> remat VALU storm).
// ---------------------------------------------------------------------------
__global__ __launch_bounds__(256, 3) void attn_mfma(const u16* __restrict__ Qh,
                                                    const u16* __restrict__ Kh,
                                                    const u16* __restrict__ Vt,
                                                    u16* __restrict__ AO) {
    __shared__ __align__(16) u16 Ks[2][512 * 8];
    __shared__ __align__(16) u16 Vs[2][512 * 8];

    const int t = threadIdx.x;
    const int wave = t >> 6, lane = t & 63;
    const int l31 = lane & 31, half = lane >> 5;

    // XCD-grouped decode: bid&7 -> XCD slot; 12 (b,h) per XCD; 8 q-blocks each
    const int bid = blockIdx.x;
    const int xcd = bid & 7, idx = bid >> 3;      // idx 0..95
    const int bh = xcd * 12 + (idx % 12);
    const int q0 = (idx / 12) * 128;
    const int b = bh / NHEADS, h = bh - b * NHEADS;

    const u16* Kb = Kh + (size_t)bh * SEQ * HD;
    const u16* Vb = Vt + (size_t)bh * HD * SEQ;
    const int qb = q0 + wave * 32;

    // Q fragments (B-operand: n = query = l31, k = tt*16 + half*8 + j)
    short8 qf[4];
#pragma unroll
    for (int tt = 0; tt < 4; ++tt)
        qf[tt] = *(const short8*)(Qh + ((size_t)bh * SEQ + qb + l31) * HD +
                                  tt * 16 + half * 8);

    f32x16 o[2]; // [d-tile]
#pragma unroll
    for (int dt = 0; dt < 2; ++dt)
#pragma unroll
        for (int r = 0; r < 16; ++r) o[dt][r] = 0.f;
    float lp = 0.f;

    // staging lane->global mapping (inverse of slot swizzle)
    const int arl = lane >> 3;            // row within 8-row span
    const int acc8 = (lane & 7) ^ arl;    // chunk 0..7
    // fragment-read bank spread piece
    const int fx8 = l31 & 7;

    auto stage = [&](int j0, int db) {
#pragma unroll
        for (int it = 0; it < 2; ++it) {
            const int cb = it * 256 + wave * 64; // span base, wave-uniform
            const int r0 = (cb >> 6) * 8 + arl;  // row 0..63
            gl2lds16(Kb + (size_t)(j0 + r0) * HD + acc8 * 8,
                     (char*)Ks[db] + cb * 16);
            gl2lds16(Vb + (size_t)r0 * SEQ + j0 + acc8 * 8,
                     (char*)Vs[db] + cb * 16);
        }
    };

    stage(0, 0);
#pragma unroll 2
    for (int jt = 0; jt < SEQ / 64; ++jt) {
        const int db = jt & 1;
        VM0;   // own tile-jt loads done (issued one full compute phase ago)
        bar(); // all waves' loads landed; all waves done reading buf db^1
        if (jt + 1 < SEQ / 64) stage((jt + 1) * 64, db ^ 1);
        const u16* Ksl = Ks[db];
        const u16* Vsl = Vs[db];

        // ---- S^T: both 32-key tiles, independent MFMA chains first ----
        f32x16 sa0, sa1;
#pragma unroll
        for (int r = 0; r < 16; ++r) { sa0[r] = 0.f; sa1[r] = 0.f; }
#pragma unroll
        for (int tt = 0; tt < 4; ++tt) {
            short8 kf0 = *(const short8*)&Ksl[
                ((((l31 >> 3)) * 64) + fx8 * 8 + ((2 * tt + half) ^ fx8)) * 8];
            short8 kf1 = *(const short8*)&Ksl[
                (((4 + (l31 >> 3)) * 64) + fx8 * 8 + ((2 * tt + half) ^ fx8)) * 8];
            sa0 = MFMA32(kf0, qf[tt], sa0);
            sa1 = MFMA32(kf1, qf[tt], sa1);
        }

        // ---- softmax numerators in-register (exp2 -> cvt_pk -> permlane) ----
        short8 pf0a, pf0b, pf1a, pf1b;
        {
            float p[16];
#pragma unroll
            for (int r = 0; r < 16; ++r) p[r] = EXP2(sa0[r]);
#pragma unroll
            for (int rg = 0; rg < 4; ++rg)
                lp += (p[rg * 4] + p[rg * 4 + 1]) + (p[rg * 4 + 2] + p[rg * 4 + 3]);
            u32 q[8];
#pragma unroll
            for (int i = 0; i < 8; ++i) q[i] = cvtpk(p[2 * i], p[2 * i + 1]);
            u32 d0, d1, d2, d3, e0, e1, e2, e3;
            plswap(q[0], q[2], half, d0, d2);
            plswap(q[1], q[3], half, d1, d3);
            plswap(q[4], q[6], half, e0, e2);
            plswap(q[5], q[7], half, e1, e3);
            u32x4 f0v = {d0, d1, d2, d3};
            u32x4 f1v = {e0, e1, e2, e3};
            pf0a = __builtin_bit_cast(short8, f0v);
            pf0b = __builtin_bit_cast(short8, f1v);
        }
        {
            float p[16];
#pragma unroll
            for (int r = 0; r < 16; ++r) p[r] = EXP2(sa1[r]);
#pragma unroll
            for (int rg = 0; rg < 4; ++rg)
                lp += (p[rg * 4] + p[rg * 4 + 1]) + (p[rg * 4 + 2] + p[rg * 4 + 3]);
            u32 q[8];
#pragma unroll
            for (int i = 0; i < 8; ++i) q[i] = cvtpk(p[2 * i], p[2 * i + 1]);
            u32 d0, d1, d2, d3, e0, e1, e2, e3;
            plswap(q[0], q[2], half, d0, d2);
            plswap(q[1], q[3], half, d1, d3);
            plswap(q[4], q[6], half, e0, e2);
            plswap(q[5], q[7], half, e1, e3);
            u32x4 f0v = {d0, d1, d2, d3};
            u32x4 f1v = {e0, e1, e2, e3};
            pf1a = __builtin_bit_cast(short8, f0v);
            pf1b = __builtin_bit_cast(short8, f1v);
        }

        // ---- PV: O^T += V^T @ P (4 slices of 16 keys) ----
#pragma unroll
        for (int kt = 0; kt < 2; ++kt)
#pragma unroll
            for (int s = 0; s < 2; ++s) {
                short8 pf = kt ? (s ? pf1b : pf1a) : (s ? pf0b : pf0a);
                const int c = kt * 4 + s * 2 + half; // key-slice column
#pragma unroll
                for (int dt = 0; dt < 2; ++dt) {
                    short8 vf = *(const short8*)&Vsl[
                        (((dt * 4 + (l31 >> 3)) * 64) + fx8 * 8 + (c ^ fx8)) * 8];
                    o[dt] = MFMA32(vf, pf, o[dt]);
                }
            }
    }

    // final l reduction (halves hold disjoint key subsets) and output
    const float invl = 1.f / (lp + __shfl_xor(lp, 32, 64));
    u16* ob = AO + (size_t)(b * SEQ + qb + l31) * NDIM + h * HD;
#pragma unroll
    for (int dt = 0; dt < 2; ++dt)
#pragma unroll
        for (int rg = 0; rg < 4; ++rg) {
            bf16x4 ok = {(short)f2bf(o[dt][rg * 4 + 0] * invl),
                         (short)f2bf(o[dt][rg * 4 + 1] * invl),
                         (short)f2bf(o[dt][rg * 4 + 2] * invl),
                         (short)f2bf(o[dt][rg * 4 + 3] * invl)};
            *(bf16x4*)(ob + dt * 32 + rg * 8 + half * 4) = ok;
        }
}

// ---------------------------------------------------------------------------
extern "C" void kernel_launch(void* const* d_in, const int* in_sizes, int n_in,
                              void* d_out, int out_size, void* d_ws, size_t ws_size,
                              hipStream_t stream) {
    const float* x    = (const float*)d_in[0];
    const float* Wq   = (const float*)d_in[1];
    const float* Wk   = (const float*)d_in[2];
    const float* Wv   = (const float*)d_in[3];
    const float* Wo   = (const float*)d_in[4];
    const float* s_qk = (const float*)d_in[5];
    float* out = (float*)d_out;

    char* w = (char*)d_ws;
    const size_t TE = (size_t)MROWS * NDIM;
    u16* xb   = (u16*)w;                    w += TE * 2;
    u16* Wqkv = (u16*)w;                    w += (size_t)3 * NDIM * NDIM * 2;
    u16* Wob  = (u16*)w;                    w += (size_t)NDIM * NDIM * 2;
    u16* Qh   = (u16*)w;                    w += TE * 2;
    u16* Kh   = (u16*)w;                    w += TE * 2;
    u16* Vt   = (u16*)w;                    w += TE * 2;
    u16* ao   = (u16*)w;

    castall<<<6144 + 4 * 576, 256, 0, stream>>>(x, Wq, Wk, Wv, Wo, xb, Wqkv, Wob);

    // Fused QKV projection: 256 uniform blocks (256^2 tile + post-loop 32x256
    // sliver of the 9th N-strip) — exactly one scheduling round, no tail.
    gemm256_qkv<<<256, 512, 0, stream>>>(xb, Wqkv, Vt, s_qk, Qh, Kh);

    // Flash attention, XCD-grouped 1D grid (768 = 8 xcd x 12 bh x 8 qblk)
    attn_mfma<<<768, 256, 0, stream>>>(Qh, Kh, Vt, ao);

    // Output projection: NX = 768/128 = 6
    gemm_bf16<0><<<6 * 64, 256, 0, stream>>>(
        ao, Wob, out, NDIM, nullptr, nullptr, nullptr, 6);
}

// Round 9
// 175.144 us; speedup vs baseline: 1.3468x; 1.0919x over previous
//
#include <hip/hip_runtime.h>
#include <hip/hip_bf16.h>
#include <math.h>

#define NDIM 768
#define NHEADS 12
#define HD 64
#define SEQ 1024
#define BATCH 8
#define MROWS (BATCH * SEQ)          // 8192
#define SQRT_DIM 27.712812921102035f // 1/SCALE_PARAM_INIT
#define LOG2E 1.4426950408889634f

typedef unsigned short u16;
typedef unsigned int u32;
typedef __attribute__((ext_vector_type(8))) short short8;   // 8 bf16 = 4 VGPRs
typedef __attribute__((ext_vector_type(4))) short bf16x4;   // 4 bf16 = 2 VGPRs
typedef __attribute__((ext_vector_type(4))) float f32x4;
typedef __attribute__((ext_vector_type(16))) float f32x16;
typedef __attribute__((ext_vector_type(2))) u32 u32x2;
typedef __attribute__((ext_vector_type(4))) u32 u32x4;

#define MFMA16(a, b, c) __builtin_amdgcn_mfma_f32_16x16x32_bf16(a, b, c, 0, 0, 0)
#define MFMA32(a, b, c) __builtin_amdgcn_mfma_f32_32x32x16_bf16(a, b, c, 0, 0, 0)

#if __has_builtin(__builtin_amdgcn_exp2f)
#define EXP2(x) __builtin_amdgcn_exp2f(x)
#else
#define EXP2(x) exp2f(x)
#endif

__device__ inline u16 f2bf(float f) {
    __hip_bfloat16 h = __float2bfloat16(f);
    return *reinterpret_cast<u16*>(&h);
}

// RNE round a,b to bf16 and pack into one u32 (a = low half). No NaN check —
// callers guarantee finite inputs.
__device__ inline u32 rne_pack(float a, float b) {
    u32 ua = __builtin_bit_cast(u32, a), ub = __builtin_bit_cast(u32, b);
    ua = (ua + 0x7fffu + ((ua >> 16) & 1u)) >> 16;
    ub = (ub + 0x7fffu + ((ub >> 16) & 1u)) >> 16;
    return (ub << 16) | ua;
}

// single-instruction packed f32->bf16 RNE convert (no builtin on gfx950; T12)
__device__ inline u32 cvtpk(float a, float b) {
    u32 r;
    asm("v_cvt_pk_bf16_f32 %0, %1, %2" : "=v"(r) : "v"(a), "v"(b));
    return r;
}

// async 16B global->LDS. LDS dest is wave-uniform base; HW adds lane*16.
__device__ inline void gl2lds16(const void* g, void* l) {
    __builtin_amdgcn_global_load_lds((const __attribute__((address_space(1))) void*)g,
                                     (__attribute__((address_space(3))) void*)l, 16, 0, 0);
}

// compiler-fenced raw barrier (NO vmcnt drain — that is the whole point)
__device__ inline void bar() {
    asm volatile("" ::: "memory");
    __builtin_amdgcn_s_barrier();
    asm volatile("" ::: "memory");
}
#define LGKM0 asm volatile("s_waitcnt lgkmcnt(0)" ::: "memory")
#define VM0   asm volatile("s_waitcnt vmcnt(0)" ::: "memory")

// half-swap: x[i] = i<32 ? a[i] : b[i-32]; y[i] = i<32 ? a[i+32] : b[i].
// One v_permlane32_swap_b32 yields both outputs (T12); shfl fallback.
__device__ inline void plswap(u32 a, u32 b, int half, u32& x, u32& y) {
#if __has_builtin(__builtin_amdgcn_permlane32_swap)
    u32x2 r = __builtin_amdgcn_permlane32_swap(a, b, false, false);
    x = r[0]; y = r[1];
#else
    u32 oa = __shfl_xor(a, 32, 64), ob = __shfl_xor(b, 32, 64);
    x = half ? ob : a;
    y = half ? b : oa;
#endif
}

// ---------------------------------------------------------------------------
// One fused cast kernel: x (6144 blocks) + Wq/Wk/Wv -> Wqkv, Wo -> Wob.
// ---------------------------------------------------------------------------
__global__ __launch_bounds__(256) void castall(const float* __restrict__ x,
                                               const float* __restrict__ Wq,
                                               const float* __restrict__ Wk,
                                               const float* __restrict__ Wv,
                                               const float* __restrict__ Wo,
                                               u16* __restrict__ xb,
                                               u16* __restrict__ Wqkv,
                                               u16* __restrict__ Wob) {
    const int WB = (NDIM * NDIM) / 1024; // 576 blocks per weight
    int blk = blockIdx.x;
    const float* s;
    u16* d;
    int base;
    if (blk < 6144) {
        s = x; d = xb; base = blk * 1024;
    } else {
        int wsel = (blk - 6144) / WB, r = (blk - 6144) % WB;
        base = r * 1024;
        if (wsel == 0)      { s = Wq; d = Wqkv; }
        else if (wsel == 1) { s = Wk; d = Wqkv + NDIM * NDIM; }
        else if (wsel == 2) { s = Wv; d = Wqkv + 2 * NDIM * NDIM; }
        else                { s = Wo; d = Wob; }
    }
    int i = base + threadIdx.x * 4;
    float4 v = *(const float4*)(s + i);
    uint2 o = make_uint2(rne_pack(v.x, v.y), rne_pack(v.z, v.w));
    *(uint2*)(d + i) = o;
}

// ---------------------------------------------------------------------------
// 256x256 / BK=64 / 8-wave 8-phase GEMM (T3+T4+T5) for the fused QKV
// projection: C = A[8192,768] @ B[2304,768]^T with fused cosine-norm (Q/K)
// and transposed-V epilogue. Grid = 256 = exactly one scheduling round over
// N-tiles 0..7; the 9th N-strip is handled by the separate vtail kernel.
// (r7: sliver in-loop -> spill, 133us. r8: sliver post-loop -> L3-latency
// serial tail, 64us. r6: in-kernel tail round -> 44us but carried a
// dispatch-order write race. This version = clean full path only.)
// ---------------------------------------------------------------------------
__global__ __launch_bounds__(512, 2) void gemm256_qkv(const u16* __restrict__ A,
                                                      const u16* __restrict__ B,
                                                      u16* __restrict__ Vt,
                                                      const float* __restrict__ s_qk,
                                                      u16* __restrict__ Qdst,
                                                      u16* __restrict__ Kdst) {
    constexpr int K = NDIM;     // 768
    constexpr int NT = K / 64;  // 12 K-tiles
    __shared__ __align__(16) u16 As[2][2][128 * 64]; // [dbuf][half][r*8+slot]
    __shared__ __align__(16) u16 Bs[2][2][128 * 64];

    const int t = threadIdx.x;
    const int wave = t >> 6, lane = t & 63;
    const int quad = lane >> 4, l16 = lane & 15;
    const int fx = l16 & 7;                  // fragment-read XOR key
    const int blk = blockIdx.x;

    // half-tile stage: 128 rows x 64 k = 16 KB = 512 thr x 2 x 16B.
    const int srow = lane >> 3;
    const int schk = (lane & 7) ^ srow;
    auto stg = [&](const u16* src, u16* dst) {
#pragma unroll
        for (int it = 0; it < 2; ++it) {
            const int cb = it * 512 + wave * 64; // slot base, wave-uniform
            const int r = (cb >> 3) + srow;      // row 0..127
            gl2lds16(src + (size_t)r * K + schk * 8, (char*)dst + cb * 16);
        }
    };

    const int wm = wave >> 2, wn = wave & 3; // 2 x 4 wave grid, 128x64 each
    const int xcd = blk & 7, local = blk >> 3;            // 0..31
    const int bm = xcd * 1024 + (local >> 3) * 256;       // 4 M-tiles/XCD
    const int bn = (local & 7) * 256;                     // N-tiles 0..7

    f32x4 acc[8][4];
#pragma unroll
    for (int i = 0; i < 8; ++i)
#pragma unroll
        for (int j = 0; j < 4; ++j) acc[i][j] = (f32x4){0.f, 0.f, 0.f, 0.f};

    const u16* Ag = A + (size_t)bm * K;
    const u16* Bg = B + (size_t)bn * K;

    // prologue: tile0 {A,B} + tile1 {B}; wait tile0 (12 issued, 4 may fly)
    stg(Ag,                        As[0][0]);
    stg(Ag + (size_t)128 * K,      As[0][1]);
    stg(Bg,                        Bs[0][0]);
    stg(Bg + (size_t)128 * K,      Bs[0][1]);
    stg(Bg + 64,                   Bs[1][0]);
    stg(Bg + (size_t)128 * K + 64, Bs[1][1]);
    asm volatile("s_waitcnt vmcnt(4)" ::: "memory");
    bar();

    short8 a[4][2], b0[2][2], b1[2][2];
    const int rb0 = (wn & 1) * 64; // this wave's B-row base within its half

#pragma unroll 2
    for (int T = 0; T < NT; ++T) {
        const int db = T & 1;
        u16* Asl = As[db][wm];
        u16* Bsl = Bs[db][wn >> 1];
        const u16* An = Ag + (size_t)(T + 1) * 64;
        const u16* Bn = Bg + (size_t)(T + 2) * 64;

        // ---- P0: read A[mi0-3] + B[ni0-1]; stage A(T+1)h0; MFMA Q(0,0) ----
#pragma unroll
        for (int mi = 0; mi < 4; ++mi) {
            const int r = mi * 16 + l16;
#pragma unroll
            for (int kk = 0; kk < 2; ++kk)
                a[mi][kk] = *(const short8*)&Asl[(r * 8 + ((kk * 4 + quad) ^ fx)) * 8];
        }
#pragma unroll
        for (int ni = 0; ni < 2; ++ni) {
            const int r = rb0 + ni * 16 + l16;
#pragma unroll
            for (int kk = 0; kk < 2; ++kk)
                b0[ni][kk] = *(const short8*)&Bsl[(r * 8 + ((kk * 4 + quad) ^ fx)) * 8];
        }
        if (T + 1 < NT) stg(An, As[db ^ 1][0]);
        bar();
        LGKM0;
        __builtin_amdgcn_s_setprio(1);
#pragma unroll
        for (int kk = 0; kk < 2; ++kk)
#pragma unroll
            for (int mi = 0; mi < 4; ++mi)
#pragma unroll
                for (int ni = 0; ni < 2; ++ni)
                    acc[mi][ni] = MFMA16(a[mi][kk], b0[ni][kk], acc[mi][ni]);
        __builtin_amdgcn_s_setprio(0);
        bar();

        // ---- P1: read B[ni2-3]; stage A(T+1)h1; MFMA Q(0,1) ----
#pragma unroll
        for (int ni = 0; ni < 2; ++ni) {
            const int r = rb0 + (ni + 2) * 16 + l16;
#pragma unroll
            for (int kk = 0; kk < 2; ++kk)
                b1[ni][kk] = *(const short8*)&Bsl[(r * 8 + ((kk * 4 + quad) ^ fx)) * 8];
        }
        if (T + 1 < NT) stg(An + (size_t)128 * K, As[db ^ 1][1]);
        bar();
        LGKM0;
        __builtin_amdgcn_s_setprio(1);
#pragma unroll
        for (int kk = 0; kk < 2; ++kk)
#pragma unroll
            for (int mi = 0; mi < 4; ++mi)
#pragma unroll
                for (int ni = 0; ni < 2; ++ni)
                    acc[mi][ni + 2] = MFMA16(a[mi][kk], b1[ni][kk], acc[mi][ni + 2]);
        __builtin_amdgcn_s_setprio(0);
        bar();

        // ---- P2: read A[mi4-7]; stage B(T+2)h0; MFMA Q(1,1) ----
#pragma unroll
        for (int mi = 0; mi < 4; ++mi) {
            const int r = (mi + 4) * 16 + l16;
#pragma unroll
            for (int kk = 0; kk < 2; ++kk)
                a[mi][kk] = *(const short8*)&Asl[(r * 8 + ((kk * 4 + quad) ^ fx)) * 8];
        }
        if (T + 2 < NT) stg(Bn, Bs[db][0]);
        bar();
        LGKM0;
        __builtin_amdgcn_s_setprio(1);
#pragma unroll
        for (int kk = 0; kk < 2; ++kk)
#pragma unroll
            for (int mi = 0; mi < 4; ++mi)
#pragma unroll
                for (int ni = 0; ni < 2; ++ni)
                    acc[mi + 4][ni + 2] = MFMA16(a[mi][kk], b1[ni][kk], acc[mi + 4][ni + 2]);
        __builtin_amdgcn_s_setprio(0);
        bar();

        // ---- P3: stage B(T+2)h1; MFMA Q(1,0); counted vmcnt; bar ----
        if (T + 2 < NT) stg(Bn + (size_t)128 * K, Bs[db][1]);
        bar();
        __builtin_amdgcn_s_setprio(1);
#pragma unroll
        for (int kk = 0; kk < 2; ++kk)
#pragma unroll
            for (int mi = 0; mi < 4; ++mi)
#pragma unroll
                for (int ni = 0; ni < 2; ++ni)
                    acc[mi + 4][ni] = MFMA16(a[mi][kk], b0[ni][kk], acc[mi + 4][ni]);
        __builtin_amdgcn_s_setprio(0);
        if (T + 2 < NT) {
            asm volatile("s_waitcnt vmcnt(4)" ::: "memory"); // tile T+1 resident
        } else {
            VM0; // drains A(NT-1) too (last two iters)
        }
        bar();
    }

    // ---- fused QKV epilogue (wave's 64 cols = exactly one head-group) ----
    const int cg = (bn + wn * 64) >> 6; // 0..31 here
    if (cg >= 2 * NHEADS) {
        // V path: transposed bf16 write, 4 consecutive tokens packed -> 8B
        const int h = cg - 2 * NHEADS;
#pragma unroll
        for (int mi = 0; mi < 8; ++mi) {
            const int row = bm + wm * 128 + mi * 16 + quad * 4; // token base
            const int bb = row >> 10, n0 = row & 1023;
#pragma unroll
            for (int ni = 0; ni < 4; ++ni) {
                const int dd = ni * 16 + l16;
                uint2 pk = make_uint2(rne_pack(acc[mi][ni][0], acc[mi][ni][1]),
                                      rne_pack(acc[mi][ni][2], acc[mi][ni][3]));
                *(uint2*)(Vt + (((size_t)(bb * NHEADS + h) * HD + dd) << 10) + n0) = pk;
            }
        }
    } else {
        const bool isq = cg < NHEADS;
        const int h = isq ? cg : cg - NHEADS;
        u16* dst = isq ? Qdst : Kdst;
        const float ex = isq ? 8.f * LOG2E : 1.f;
        float sq[4];
#pragma unroll
        for (int ni = 0; ni < 4; ++ni)
            sq[ni] = s_qk[h * HD + ni * 16 + l16] * SQRT_DIM * ex;
#pragma unroll
        for (int mi = 0; mi < 8; ++mi)
#pragma unroll
            for (int r = 0; r < 4; ++r) {
                float ss = 0.f;
#pragma unroll
                for (int ni = 0; ni < 4; ++ni) ss += acc[mi][ni][r] * acc[mi][ni][r];
                ss += __shfl_xor(ss, 1, 64);
                ss += __shfl_xor(ss, 2, 64);
                ss += __shfl_xor(ss, 4, 64);
                ss += __shfl_xor(ss, 8, 64);
                float inv = 1.f / fmaxf(sqrtf(ss), 1e-6f);
                const int row = bm + wm * 128 + mi * 16 + quad * 4 + r;
                const int bb = row >> 10, tok = row & 1023;
                u16* o = dst + ((size_t)(bb * NHEADS + h) * SEQ + tok) * HD;
#pragma unroll
                for (int ni = 0; ni < 4; ++ni)
                    o[ni * 16 + l16] = f2bf(acc[mi][ni][r] * sq[ni] * inv);
            }
    }
}

// ---------------------------------------------------------------------------
// vtail: the 9th N-strip of the QKV projection — Vt rows for heads 8..11.
// C = A[8192,768] @ B[2048..2303,768]^T, transposed-V epilogue.
// 256 blocks x 512 thr, 64x128 tiles, waves 2M x 4N (wave = 32x32; fixes the
// r6 in-kernel tail whose 4Mx2N map read LDS OOB and wrote neighbors' rows).
// LDS = 3-slot ring of (A 8KB + B 16KB) = 72 KB -> 2 blk/CU (r6 reserved the
// full 128 KB -> 1/CU). Counted vmcnt(3): 3 gl2lds/thread/tile, 2 tiles in
// flight; one barrier per iter; no full drain in steady state (T4).
// ---------------------------------------------------------------------------
__global__ __launch_bounds__(512, 4) void vtail(const u16* __restrict__ A,
                                                const u16* __restrict__ B,
                                                u16* __restrict__ Vt) {
    constexpr int K = NDIM;
    constexpr int NT = K / 64; // 12
    __shared__ __align__(16) u16 Ar[3][64 * 64];  // 8 KB per slot
    __shared__ __align__(16) u16 Br[3][128 * 64]; // 16 KB per slot

    const int t = threadIdx.x;
    const int wave = t >> 6, lane = t & 63;
    const int quad = lane >> 4, l16 = lane & 15;
    const int fx = l16 & 7;
    const int srow = lane >> 3;
    const int schk = (lane & 7) ^ srow;

    const int q = blockIdx.x;            // 0..255
    const int bm = (q >> 1) * 64;        // 128 M-strips of 64 rows
    const int bcol = (q & 1) * 128;      // strip column half (0 or 128)
    const int wm2 = wave >> 2;           // 0..1 -> 32-row group
    const int wn4 = wave & 3;            // 0..3 -> 32-col group
    const u16* Ag = A + (size_t)bm * K;
    const u16* Bg = B + (size_t)(2048 + bcol) * K;

    // stage tile Tk into ring slot s: A = 1 gl2lds/thread, B = 2.
    auto stage = [&](int Tk, int s) {
        {
            const int cb = wave * 64;                 // 512 slots = 64 rows
            const int r = (cb >> 3) + srow;           // 0..63
            gl2lds16(Ag + (size_t)r * K + Tk * 64 + schk * 8,
                     (char*)Ar[s] + cb * 16);
        }
#pragma unroll
        for (int it = 0; it < 2; ++it) {
            const int cb = it * 512 + wave * 64;      // 1024 slots = 128 rows
            const int r = (cb >> 3) + srow;           // 0..127
            gl2lds16(Bg + (size_t)r * K + Tk * 64 + schk * 8,
                     (char*)Br[s] + cb * 16);
        }
    };

    f32x4 acc[2][2];
#pragma unroll
    for (int i = 0; i < 2; ++i)
#pragma unroll
        for (int j = 0; j < 2; ++j) acc[i][j] = (f32x4){0.f, 0.f, 0.f, 0.f};

    stage(0, 0);
    stage(1, 1);
#pragma unroll
    for (int T = 0; T < NT; ++T) {
        // outstanding: tile T (3 loads, oldest) + tile T+1 (3) if staged.
        if (T + 1 < NT) asm volatile("s_waitcnt vmcnt(3)" ::: "memory");
        else            VM0;
        bar(); // tile T resident everywhere; all waves past slot (T+2)%3 reads
        if (T + 2 < NT) stage(T + 2, (T + 2) % 3);
        const u16* Asl = Ar[T % 3];
        const u16* Bsl = Br[T % 3];
        short8 af[2][2], bf[2][2];
#pragma unroll
        for (int mi = 0; mi < 2; ++mi) {
            const int r = wm2 * 32 + mi * 16 + l16;   // 0..63
#pragma unroll
            for (int kk = 0; kk < 2; ++kk)
                af[mi][kk] = *(const short8*)&Asl[(r * 8 + ((kk * 4 + quad) ^ fx)) * 8];
        }
#pragma unroll
        for (int ni = 0; ni < 2; ++ni) {
            const int r = wn4 * 32 + ni * 16 + l16;   // 0..127
#pragma unroll
            for (int kk = 0; kk < 2; ++kk)
                bf[ni][kk] = *(const short8*)&Bsl[(r * 8 + ((kk * 4 + quad) ^ fx)) * 8];
        }
        __builtin_amdgcn_s_setprio(1);
#pragma unroll
        for (int kk = 0; kk < 2; ++kk)
#pragma unroll
            for (int mi = 0; mi < 2; ++mi)
#pragma unroll
                for (int ni = 0; ni < 2; ++ni)
                    acc[mi][ni] = MFMA16(af[mi][kk], bf[ni][kk], acc[mi][ni]);
        __builtin_amdgcn_s_setprio(0);
    }

    // V epilogue (transposed, 4 tokens packed -> 8B), heads 8..11
#pragma unroll
    for (int mi = 0; mi < 2; ++mi) {
        const int row0 = bm + wm2 * 32 + mi * 16 + quad * 4; // within own 64
        const int bb = row0 >> 10, n0 = row0 & 1023;
#pragma unroll
        for (int ni = 0; ni < 2; ++ni) {
            const int cv = bcol + wn4 * 32 + ni * 16 + l16;  // 0..255
            const int h = 8 + (cv >> 6), dd = cv & 63;
            uint2 pk = make_uint2(rne_pack(acc[mi][ni][0], acc[mi][ni][1]),
                                  rne_pack(acc[mi][ni][2], acc[mi][ni][3]));
            *(uint2*)(Vt + (((size_t)(bb * NHEADS + h) * HD + dd) << 10) + n0) = pk;
        }
    }
}

// ---------------------------------------------------------------------------
// bf16 MFMA GEMM: C = A[M,768] @ B[N,768]^T, fp32 accum. 128x128 tile,
// double-buffered BK=32 (one barrier/iter). Kept for the output projection.
// ---------------------------------------------------------------------------
template <int EPI>
__global__ __launch_bounds__(256) void gemm_bf16(const u16* __restrict__ A,
                                                 const u16* __restrict__ B,
                                                 void* __restrict__ C, int N,
                                                 const float* __restrict__ s_qk,
                                                 u16* __restrict__ Qdst,
                                                 u16* __restrict__ Kdst,
                                                 int NX) {
    constexpr int K = NDIM;
    constexpr int NKT = K / 32; // 24 K-tiles
    __shared__ __align__(16) u16 As[2][4096]; // 8 KB per buffer
    __shared__ __align__(16) u16 Bs[2][4096];
    const int t = threadIdx.x;
    const int wave = t >> 6, lane = t & 63;
    const int quad = lane >> 4, l16 = lane & 15;
    const int wx = (wave & 1) * 64, wy = (wave >> 1) * 64;
    const int blk = blockIdx.x;
    const int xcd = blk & 7, local = blk >> 3;
    const int bm = (xcd * 8 + local / NX) * 128;
    const int bn = (local % NX) * 128;

    f32x4 acc[4][4];
#pragma unroll
    for (int i = 0; i < 4; ++i)
#pragma unroll
        for (int j = 0; j < 4; ++j) acc[i][j] = (f32x4){0.f, 0.f, 0.f, 0.f};

    const int srl = lane >> 2;
    const int skc = (lane & 3) ^ ((lane >> 3) & 3);
    auto stage = [&](int k0, int bsel) {
#pragma unroll
        for (int it = 0; it < 2; ++it) {
            const int cb = it * 256 + wave * 64;
            const int row = (cb >> 6) * 16 + srl;
            gl2lds16(A + (size_t)(bm + row) * K + k0 + skc * 8,
                     (char*)As[bsel] + cb * 16);
            gl2lds16(B + (size_t)(bn + row) * K + k0 + skc * 8,
                     (char*)Bs[bsel] + cb * 16);
        }
    };
    const int fxor = (l16 >> 1) & 3;

    stage(0, 0);
#pragma unroll
    for (int kt = 0; kt < NKT; ++kt) {
        __syncthreads();
        if (kt + 1 < NKT) stage((kt + 1) * 32, (kt + 1) & 1);
        const int b = kt & 1;
        short8 af[4], bfr[4];
#pragma unroll
        for (int i = 0; i < 4; ++i)
            af[i] = *(const short8*)&As[b][
                ((((wy >> 4) + i) * 64 + l16 * 4 + (quad ^ fxor)) * 8)];
#pragma unroll
        for (int j = 0; j < 4; ++j)
            bfr[j] = *(const short8*)&Bs[b][
                ((((wx >> 4) + j) * 64 + l16 * 4 + (quad ^ fxor)) * 8)];
#pragma unroll
        for (int i = 0; i < 4; ++i)
#pragma unroll
            for (int j = 0; j < 4; ++j) acc[i][j] = MFMA16(af[i], bfr[j], acc[i][j]);
    }

    if constexpr (EPI == 0) {
#pragma unroll
        for (int i = 0; i < 4; ++i)
#pragma unroll
            for (int j = 0; j < 4; ++j)
#pragma unroll
                for (int r = 0; r < 4; ++r) {
                    const int row = bm + wy + i * 16 + quad * 4 + r;
                    const int col = bn + wx + j * 16 + l16;
                    ((float*)C)[(size_t)row * N + col] = acc[i][j][r];
                }
    }
}

// ---------------------------------------------------------------------------
// MFMA flash attention, 32x32x16, no-max softmax. 256 threads = 4 waves;
// each wave owns 32 queries -> block = 128 queries; streams 64-key tiles.
// __launch_bounds__(256,3): 3 waves/EU = grid's 3 blocks/CU while allowing
// ~168 VGPR (r3 shipped at 64 VGPR -> remat VALU storm).
// ---------------------------------------------------------------------------
__global__ __launch_bounds__(256, 3) void attn_mfma(const u16* __restrict__ Qh,
                                                    const u16* __restrict__ Kh,
                                                    const u16* __restrict__ Vt,
                                                    u16* __restrict__ AO) {
    __shared__ __align__(16) u16 Ks[2][512 * 8];
    __shared__ __align__(16) u16 Vs[2][512 * 8];

    const int t = threadIdx.x;
    const int wave = t >> 6, lane = t & 63;
    const int l31 = lane & 31, half = lane >> 5;

    // XCD-grouped decode: bid&7 -> XCD slot; 12 (b,h) per XCD; 8 q-blocks each
    const int bid = blockIdx.x;
    const int xcd = bid & 7, idx = bid >> 3;      // idx 0..95
    const int bh = xcd * 12 + (idx % 12);
    const int q0 = (idx / 12) * 128;
    const int b = bh / NHEADS, h = bh - b * NHEADS;

    const u16* Kb = Kh + (size_t)bh * SEQ * HD;
    const u16* Vb = Vt + (size_t)bh * HD * SEQ;
    const int qb = q0 + wave * 32;

    // Q fragments (B-operand: n = query = l31, k = tt*16 + half*8 + j)
    short8 qf[4];
#pragma unroll
    for (int tt = 0; tt < 4; ++tt)
        qf[tt] = *(const short8*)(Qh + ((size_t)bh * SEQ + qb + l31) * HD +
                                  tt * 16 + half * 8);

    f32x16 o[2]; // [d-tile]
#pragma unroll
    for (int dt = 0; dt < 2; ++dt)
#pragma unroll
        for (int r = 0; r < 16; ++r) o[dt][r] = 0.f;
    float lp = 0.f;

    // staging lane->global mapping (inverse of slot swizzle)
    const int arl = lane >> 3;            // row within 8-row span
    const int acc8 = (lane & 7) ^ arl;    // chunk 0..7
    // fragment-read bank spread piece
    const int fx8 = l31 & 7;

    auto stage = [&](int j0, int db) {
#pragma unroll
        for (int it = 0; it < 2; ++it) {
            const int cb = it * 256 + wave * 64; // span base, wave-uniform
            const int r0 = (cb >> 6) * 8 + arl;  // row 0..63
            gl2lds16(Kb + (size_t)(j0 + r0) * HD + acc8 * 8,
                     (char*)Ks[db] + cb * 16);
            gl2lds16(Vb + (size_t)r0 * SEQ + j0 + acc8 * 8,
                     (char*)Vs[db] + cb * 16);
        }
    };

    stage(0, 0);
#pragma unroll 2
    for (int jt = 0; jt < SEQ / 64; ++jt) {
        const int db = jt & 1;
        VM0;   // own tile-jt loads done (issued one full compute phase ago)
        bar(); // all waves' loads landed; all waves done reading buf db^1
        if (jt + 1 < SEQ / 64) stage((jt + 1) * 64, db ^ 1);
        const u16* Ksl = Ks[db];
        const u16* Vsl = Vs[db];

        // ---- S^T: both 32-key tiles, independent MFMA chains first ----
        f32x16 sa0, sa1;
#pragma unroll
        for (int r = 0; r < 16; ++r) { sa0[r] = 0.f; sa1[r] = 0.f; }
#pragma unroll
        for (int tt = 0; tt < 4; ++tt) {
            short8 kf0 = *(const short8*)&Ksl[
                ((((l31 >> 3)) * 64) + fx8 * 8 + ((2 * tt + half) ^ fx8)) * 8];
            short8 kf1 = *(const short8*)&Ksl[
                (((4 + (l31 >> 3)) * 64) + fx8 * 8 + ((2 * tt + half) ^ fx8)) * 8];
            sa0 = MFMA32(kf0, qf[tt], sa0);
            sa1 = MFMA32(kf1, qf[tt], sa1);
        }

        // ---- softmax numerators in-register (exp2 -> cvt_pk -> permlane) ----
        short8 pf0a, pf0b, pf1a, pf1b;
        {
            float p[16];
#pragma unroll
            for (int r = 0; r < 16; ++r) p[r] = EXP2(sa0[r]);
#pragma unroll
            for (int rg = 0; rg < 4; ++rg)
                lp += (p[rg * 4] + p[rg * 4 + 1]) + (p[rg * 4 + 2] + p[rg * 4 + 3]);
            u32 q[8];
#pragma unroll
            for (int i = 0; i < 8; ++i) q[i] = cvtpk(p[2 * i], p[2 * i + 1]);
            u32 d0, d1, d2, d3, e0, e1, e2, e3;
            plswap(q[0], q[2], half, d0, d2);
            plswap(q[1], q[3], half, d1, d3);
            plswap(q[4], q[6], half, e0, e2);
            plswap(q[5], q[7], half, e1, e3);
            u32x4 f0v = {d0, d1, d2, d3};
            u32x4 f1v = {e0, e1, e2, e3};
            pf0a = __builtin_bit_cast(short8, f0v);
            pf0b = __builtin_bit_cast(short8, f1v);
        }
        {
            float p[16];
#pragma unroll
            for (int r = 0; r < 16; ++r) p[r] = EXP2(sa1[r]);
#pragma unroll
            for (int rg = 0; rg < 4; ++rg)
                lp += (p[rg * 4] + p[rg * 4 + 1]) + (p[rg * 4 + 2] + p[rg * 4 + 3]);
            u32 q[8];
#pragma unroll
            for (int i = 0; i < 8; ++i) q[i] = cvtpk(p[2 * i], p[2 * i + 1]);
            u32 d0, d1, d2, d3, e0, e1, e2, e3;
            plswap(q[0], q[2], half, d0, d2);
            plswap(q[1], q[3], half, d1, d3);
            plswap(q[4], q[6], half, e0, e2);
            plswap(q[5], q[7], half, e1, e3);
            u32x4 f0v = {d0, d1, d2, d3};
            u32x4 f1v = {e0, e1, e2, e3};
            pf1a = __builtin_bit_cast(short8, f0v);
            pf1b = __builtin_bit_cast(short8, f1v);
        }

        // ---- PV: O^T += V^T @ P (4 slices of 16 keys) ----
#pragma unroll
        for (int kt = 0; kt < 2; ++kt)
#pragma unroll
            for (int s = 0; s < 2; ++s) {
                short8 pf = kt ? (s ? pf1b : pf1a) : (s ? pf0b : pf0a);
                const int c = kt * 4 + s * 2 + half; // key-slice column
#pragma unroll
                for (int dt = 0; dt < 2; ++dt) {
                    short8 vf = *(const short8*)&Vsl[
                        (((dt * 4 + (l31 >> 3)) * 64) + fx8 * 8 + (c ^ fx8)) * 8];
                    o[dt] = MFMA32(vf, pf, o[dt]);
                }
            }
    }

    // final l reduction (halves hold disjoint key subsets) and output
    const float invl = 1.f / (lp + __shfl_xor(lp, 32, 64));
    u16* ob = AO + (size_t)(b * SEQ + qb + l31) * NDIM + h * HD;
#pragma unroll
    for (int dt = 0; dt < 2; ++dt)
#pragma unroll
        for (int rg = 0; rg < 4; ++rg) {
            bf16x4 ok = {(short)f2bf(o[dt][rg * 4 + 0] * invl),
                         (short)f2bf(o[dt][rg * 4 + 1] * invl),
                         (short)f2bf(o[dt][rg * 4 + 2] * invl),
                         (short)f2bf(o[dt][rg * 4 + 3] * invl)};
            *(bf16x4*)(ob + dt * 32 + rg * 8 + half * 4) = ok;
        }
}

// ---------------------------------------------------------------------------
extern "C" void kernel_launch(void* const* d_in, const int* in_sizes, int n_in,
                              void* d_out, int out_size, void* d_ws, size_t ws_size,
                              hipStream_t stream) {
    const float* x    = (const float*)d_in[0];
    const float* Wq   = (const float*)d_in[1];
    const float* Wk   = (const float*)d_in[2];
    const float* Wv   = (const float*)d_in[3];
    const float* Wo   = (const float*)d_in[4];
    const float* s_qk = (const float*)d_in[5];
    float* out = (float*)d_out;

    char* w = (char*)d_ws;
    const size_t TE = (size_t)MROWS * NDIM;
    u16* xb   = (u16*)w;                    w += TE * 2;
    u16* Wqkv = (u16*)w;                    w += (size_t)3 * NDIM * NDIM * 2;
    u16* Wob  = (u16*)w;                    w += (size_t)NDIM * NDIM * 2;
    u16* Qh   = (u16*)w;                    w += TE * 2;
    u16* Kh   = (u16*)w;                    w += TE * 2;
    u16* Vt   = (u16*)w;                    w += TE * 2;
    u16* ao   = (u16*)w;

    castall<<<6144 + 4 * 576, 256, 0, stream>>>(x, Wq, Wk, Wv, Wo, xb, Wqkv, Wob);

    // Fused QKV projection: 256 full 256^2 tiles — exactly one round.
    gemm256_qkv<<<256, 512, 0, stream>>>(xb, Wqkv, Vt, s_qk, Qh, Kh);

    // 9th N-strip (V heads 8..11): right-sized kernel, 2 blk/CU, ~4-6 us.
    vtail<<<256, 512, 0, stream>>>(xb, Wqkv, Vt);

    // Flash attention, XCD-grouped 1D grid (768 = 8 xcd x 12 bh x 8 qblk)
    attn_mfma<<<768, 256, 0, stream>>>(Qh, Kh, Vt, ao);

    // Output projection: NX = 768/128 = 6
    gemm_bf16<0><<<6 * 64, 256, 0, stream>>>(
        ao, Wob, out, NDIM, nullptr, nullptr, nullptr, 6);
}